// Round 1
// baseline (503.170 us; speedup 1.0000x reference)
//
#include <hip/hip_runtime.h>

#define TT 512

typedef _Float16 half8 __attribute__((ext_vector_type(8)));
typedef __attribute__((ext_vector_type(4))) float floatx4;

// raw workgroup barrier (no vmcnt/lgkmcnt drain); LDS FIFO is in-order per CU,
// validated R6-R12 (cross-wave write->barrier->read is bit-exact).
#define BAR() do { __asm__ volatile("" ::: "memory"); \
                   __builtin_amdgcn_s_barrier();      \
                   __asm__ volatile("" ::: "memory"); } while (0)

__device__ __forceinline__ float fast_tanh(float z) {
    const float e = __expf(2.f * z);
    return 1.f - __fdividef(2.f, e + 1.f);
}
__device__ __forceinline__ float f4e(const float4& v, int r) {
    return (r == 0) ? v.x : (r == 1) ? v.y : (r == 2) ? v.z : v.w;
}
__device__ __forceinline__ unsigned pk16(float a, float b) {
    const unsigned ua = __builtin_bit_cast(unsigned short, (_Float16)a);
    const unsigned ub = __builtin_bit_cast(unsigned short, (_Float16)b);
    return ua | (ub << 16);
}

// Batch-split wave-local recurrence: 128 blocks x 2 waves.
// Wave 0 = full layer-0 recurrence for 16 batch rows (4 M-tiles, 8 MFMA/step);
// Wave 1 = full layer-1 recurrence + FC. h0 handoff via 8-entry LDS ring,
// one raw barrier per 4-step superstep (wave 1 lags 4 steps). The per-step
// h(t-1)->B-fragment repack is a SAME-WAVE LDS write+readback (in-order DS
// pipe, no barrier). Ring layout: dword(rp,n) at rp*32 + (n ^ 16*((rp>>2)&1))
// -> 2-way banks on both the 8 writes (rp=8mt+2g+d) and 8 reads (rp=16kt+4g+j).
// Arithmetic bit-compatible with R10 (same fast_tanh, RTNE pk16, same MFMA
// accumulator pairing; zero B-fragment first step == scalar init exactly).
__global__ void __launch_bounds__(128, 1)
rnn2_ws(const float* __restrict__ x,
        const float* __restrict__ W_ih0, const float* __restrict__ W_hh0,
        const float* __restrict__ b_ih0, const float* __restrict__ b_hh0,
        const float* __restrict__ W_ih1, const float* __restrict__ W_hh1,
        const float* __restrict__ b_ih1, const float* __restrict__ b_hh1,
        const float* __restrict__ W_fc, const float* __restrict__ b_fc,
        float* __restrict__ out)
{
    __shared__ int lds32[10240];   // 8 ring entries (h0) + 2 entries (h1), 4KB each

    const int tid  = threadIdx.x;
    const int lane = tid & 63;
    const int w    = tid >> 6;     // 0 = layer-0 wave, 1 = layer-1 wave
    const int g    = lane >> 4;    // 0..3 (MFMA row-group / k-group)
    const int n    = lane & 15;    // batch column
    const int b0   = blockIdx.x * 16;

    // per-lane LDS bases (int index). write: rp=8mt+2g+d -> beta=(g>>1)&1;
    // read: rp=16kt+4g+j -> beta=g&1.
    const int vw_i = 64 * g + (n ^ ((g & 2) ? 16 : 0));
    const int vr_i = 128 * g + (n ^ ((g & 1) ? 16 : 0));

    const floatx4 zero4 = {0.f, 0.f, 0.f, 0.f};

    // weights (single fp16 RTNE, as R10). Wave0: wA=W_hh0. Wave1: wA=W_ih1, wB=W_hh1.
    half8 wA[4][2], wB[4][2];
    float4 wv[4], bs[4];
    auto mkfrag = [&](const float* p, half8& h) {
#pragma unroll
        for (int j = 0; j < 8; ++j) h[j] = (_Float16)p[j];
    };

    if (w == 0) {
#pragma unroll
        for (int mt = 0; mt < 4; ++mt) {
#pragma unroll
            for (int kt = 0; kt < 2; ++kt)
                mkfrag(W_hh0 + (16 * mt + n) * 64 + 32 * kt + 8 * g, wA[mt][kt]);
            wv[mt] = *(const float4*)(W_ih0 + 16 * mt + 4 * g);
            const float4 a = *(const float4*)(b_ih0 + 16 * mt + 4 * g);
            const float4 c = *(const float4*)(b_hh0 + 16 * mt + 4 * g);
            bs[mt] = make_float4(a.x + c.x, a.y + c.y, a.z + c.z, a.w + c.w);
        }
    } else {
#pragma unroll
        for (int mt = 0; mt < 4; ++mt) {
#pragma unroll
            for (int kt = 0; kt < 2; ++kt) {
                mkfrag(W_ih1 + (16 * mt + n) * 64 + 32 * kt + 8 * g, wA[mt][kt]);
                mkfrag(W_hh1 + (16 * mt + n) * 64 + 32 * kt + 8 * g, wB[mt][kt]);
            }
            const float4 a = *(const float4*)(b_ih1 + 16 * mt + 4 * g);
            const float4 c = *(const float4*)(b_hh1 + 16 * mt + 4 * g);
            bs[mt] = make_float4(a.x + c.x, a.y + c.y, a.z + c.z, a.w + c.w);
        }
    }

    // recurrent-state B fragments; h(-1) = 0 -> MFMA adds exact +0.0
    half8 s0, s1;
#pragma unroll
    for (int j = 0; j < 8; ++j) { s0[j] = (_Float16)0.f; s1[j] = (_Float16)0.f; }

    const float* xp = x + (long)(b0 + n) * TT;
    float xv = 0.f, xn = 0.f;
    if (w == 0) { xv = xp[0]; xn = xp[1]; }

    // ---- layer-0 step: MFMA on own regs -> tanh -> pack -> ring write ->
    //      same-wave readback of next-step B fragments ----
    auto stepL0 = [&](int t) {
        floatx4 aA[4], aB[4];
#pragma unroll
        for (int mt = 0; mt < 4; ++mt) {
            aA[mt][0] = __builtin_fmaf(xv, wv[mt].x, bs[mt].x);
            aA[mt][1] = __builtin_fmaf(xv, wv[mt].y, bs[mt].y);
            aA[mt][2] = __builtin_fmaf(xv, wv[mt].z, bs[mt].z);
            aA[mt][3] = __builtin_fmaf(xv, wv[mt].w, bs[mt].w);
        }
#pragma unroll
        for (int mt = 0; mt < 4; ++mt) {
            aA[mt] = __builtin_amdgcn_mfma_f32_16x16x32_f16(wA[mt][0], s0, aA[mt], 0, 0, 0);
            aB[mt] = __builtin_amdgcn_mfma_f32_16x16x32_f16(wA[mt][1], s1, zero4, 0, 0, 0);
        }
        xv = xn; xn = xp[(t + 2) & (TT - 1)];
        const int eb = (t & 7) * 1024;
        int* wp = &lds32[eb + vw_i];
#pragma unroll
        for (int mt = 0; mt < 4; ++mt) {
            const float h0v = fast_tanh(aA[mt][0] + aB[mt][0]);
            const float h1v = fast_tanh(aA[mt][1] + aB[mt][1]);
            const float h2v = fast_tanh(aA[mt][2] + aB[mt][2]);
            const float h3v = fast_tanh(aA[mt][3] + aB[mt][3]);
            wp[256 * mt]      = (int)pk16(h0v, h1v);
            wp[256 * mt + 32] = (int)pk16(h2v, h3v);
        }
        const int* rp = &lds32[eb + vr_i];
        int4 v0, v1;
        v0.x = rp[0];   v0.y = rp[32];  v0.z = rp[64];  v0.w = rp[96];
        v1.x = rp[512]; v1.y = rp[544]; v1.z = rp[576]; v1.w = rp[608];
        s0 = __builtin_bit_cast(half8, v0);
        s1 = __builtin_bit_cast(half8, v1);
    };

    // ---- layer-1 step: ring read of h0(t) (issued first, hidden behind the
    //      hh1*h1(t-1) MFMAs on regs) -> tanh -> private-buffer repack ----
    auto stepL1 = [&](int t, bool last) {
        const int eb = (t & 7) * 1024;
        const int* rx = &lds32[eb + vr_i];
        int4 u0, u1;
        u0.x = rx[0];   u0.y = rx[32];  u0.z = rx[64];  u0.w = rx[96];
        u1.x = rx[512]; u1.y = rx[544]; u1.z = rx[576]; u1.w = rx[608];
        floatx4 aA[4], aB[4];
#pragma unroll
        for (int mt = 0; mt < 4; ++mt) {
            floatx4 b = __builtin_amdgcn_mfma_f32_16x16x32_f16(wB[mt][0], s0, zero4, 0, 0, 0);
            aB[mt]    = __builtin_amdgcn_mfma_f32_16x16x32_f16(wB[mt][1], s1, b, 0, 0, 0);
        }
        const half8 bx0 = __builtin_bit_cast(half8, u0);
        const half8 bx1 = __builtin_bit_cast(half8, u1);
#pragma unroll
        for (int mt = 0; mt < 4; ++mt) {
            floatx4 a = {bs[mt].x, bs[mt].y, bs[mt].z, bs[mt].w};
            a      = __builtin_amdgcn_mfma_f32_16x16x32_f16(wA[mt][0], bx0, a, 0, 0, 0);
            aA[mt] = __builtin_amdgcn_mfma_f32_16x16x32_f16(wA[mt][1], bx1, a, 0, 0, 0);
        }
        if (!last) {
            const int hb = 8192 + (t & 1) * 1024;
            int* wp = &lds32[hb + vw_i];
#pragma unroll
            for (int mt = 0; mt < 4; ++mt) {
                const float h0v = fast_tanh(aA[mt][0] + aB[mt][0]);
                const float h1v = fast_tanh(aA[mt][1] + aB[mt][1]);
                const float h2v = fast_tanh(aA[mt][2] + aB[mt][2]);
                const float h3v = fast_tanh(aA[mt][3] + aB[mt][3]);
                wp[256 * mt]      = (int)pk16(h0v, h1v);
                wp[256 * mt + 32] = (int)pk16(h2v, h3v);
            }
            const int* rh = &lds32[hb + vr_i];
            int4 v0, v1;
            v0.x = rh[0];   v0.y = rh[32];  v0.z = rh[64];  v0.w = rh[96];
            v1.x = rh[512]; v1.y = rh[544]; v1.z = rh[576]; v1.w = rh[608];
            s0 = __builtin_bit_cast(half8, v0);
            s1 = __builtin_bit_cast(half8, v1);
        } else {
            // final step t=511: FC dot on f32 h (matches R10 epilogue numerics)
            float p = 0.f;
#pragma unroll
            for (int mt = 0; mt < 4; ++mt) {
                const float4 wf = *(const float4*)(W_fc + 16 * mt + 4 * g);
#pragma unroll
                for (int r = 0; r < 4; ++r)
                    p = __builtin_fmaf(fast_tanh(aA[mt][r] + aB[mt][r]), f4e(wf, r), p);
            }
            p += __shfl_xor(p, 16, 64);
            p += __shfl_xor(p, 32, 64);
            if (lane < 16) out[b0 + lane] = p + b_fc[0];
        }
    };

    // ---- supersteps: wave0 writes entries [4s,4s+4); wave1 lags one superstep.
    //      Ring parity (8 entries / 4-step windows) keeps them disjoint. ----
    for (int s = 0; s < 128; ++s) {
        if (w == 0) {
            const int t = 4 * s;
            stepL0(t); stepL0(t + 1); stepL0(t + 2); stepL0(t + 3);
        } else if (s > 0) {
            const int t = 4 * (s - 1);
            stepL1(t, false); stepL1(t + 1, false); stepL1(t + 2, false); stepL1(t + 3, false);
        }
        BAR();
    }
    // wave1 epilogue: t = 508..510 normal, t = 511 + FC (entries 4..7 written in
    // superstep 127, barrier already passed; wave0 has exited).
    if (w == 1) {
        stepL1(508, false); stepL1(509, false); stepL1(510, false);
        stepL1(511, true);
    }
}

extern "C" void kernel_launch(void* const* d_in, const int* in_sizes, int n_in,
                              void* d_out, int out_size, void* d_ws, size_t ws_size,
                              hipStream_t stream) {
    const float* x     = (const float*)d_in[0];
    const float* W_ih0 = (const float*)d_in[1];
    const float* W_hh0 = (const float*)d_in[2];
    const float* b_ih0 = (const float*)d_in[3];
    const float* b_hh0 = (const float*)d_in[4];
    const float* W_ih1 = (const float*)d_in[5];
    const float* W_hh1 = (const float*)d_in[6];
    const float* b_ih1 = (const float*)d_in[7];
    const float* b_hh1 = (const float*)d_in[8];
    const float* W_fc  = (const float*)d_in[9];
    const float* b_fc  = (const float*)d_in[10];
    float* out = (float*)d_out;

    rnn2_ws<<<128, 128, 0, stream>>>(x, W_ih0, W_hh0, b_ih0, b_hh0,
                                     W_ih1, W_hh1, b_ih1, b_hh1,
                                     W_fc, b_fc, out);
}

// Round 2
// 456.453 us; speedup vs baseline: 1.1023x; 1.1023x over previous
//
#include <hip/hip_runtime.h>

#define TT 512

typedef _Float16 half4 __attribute__((ext_vector_type(4)));
typedef _Float16 half8 __attribute__((ext_vector_type(8)));
typedef __attribute__((ext_vector_type(4))) float floatx4;

// raw workgroup barrier (no vmcnt/lgkmcnt drain); LDS FIFO is in-order per CU,
// validated R6-R12 (cross-wave write->barrier->read is bit-exact).
#define BAR() do { __asm__ volatile("" ::: "memory"); \
                   __builtin_amdgcn_s_barrier();      \
                   __asm__ volatile("" ::: "memory"); } while (0)

__device__ __forceinline__ float fast_tanh(float z) {
    const float e = __expf(2.f * z);
    return 1.f - __fdividef(2.f, e + 1.f);
}
__device__ __forceinline__ float f4e(const float4& v, int r) {
    return (r == 0) ? v.x : (r == 1) ? v.y : (r == 2) ? v.z : v.w;
}
__device__ __forceinline__ unsigned pk16(float a, float b) {
    const unsigned ua = __builtin_bit_cast(unsigned short, (_Float16)a);
    const unsigned ub = __builtin_bit_cast(unsigned short, (_Float16)b);
    return ua | (ub << 16);
}

// Register-resident recurrence: 128 blocks x 2 waves (wave0 = layer 0,
// wave1 = layer 1 + FC), 16 batch rows per block.
// KEY IDENTITY: for mfma_f32_16x16x16f16 the B-operand fragment layout
// (lane: col=l&15, k=4*(l>>4)+j) equals the C/D output layout (col=l&15,
// row=4*(l>>4)+reg). Splitting the 64-K recurrence GEMM into 4 accumulating
// K=16 MFMAs makes each tanh'd+fp16-packed D tile directly reusable as the
// next step's B fragment -> the serial h->h loop has NO LDS / cross-lane ops.
// L0->L1 handoff keeps the 8-entry LDS ring (2-way-conflict swizzle), read
// off the critical path; one raw barrier per 4-step superstep (wave1 lags 4).
// Numerics: same fp16 RTNE state quantization as R10; K-split only perturbs
// f32 accumulation order (few ULP).
__global__ void __launch_bounds__(128, 1)
rnn2_reg(const float* __restrict__ x,
         const float* __restrict__ W_ih0, const float* __restrict__ W_hh0,
         const float* __restrict__ b_ih0, const float* __restrict__ b_hh0,
         const float* __restrict__ W_ih1, const float* __restrict__ W_hh1,
         const float* __restrict__ b_ih1, const float* __restrict__ b_hh1,
         const float* __restrict__ W_fc, const float* __restrict__ b_fc,
         float* __restrict__ out)
{
    __shared__ int lds32[8192];    // 8-entry h0 ring, 4KB/entry

    const int tid  = threadIdx.x;
    const int lane = tid & 63;
    const int w    = tid >> 6;     // 0 = layer-0 wave, 1 = layer-1 wave
    const int g    = lane >> 4;    // MFMA lane group
    const int n    = lane & 15;    // batch column
    const int b0   = blockIdx.x * 16;

    // ring swizzle (validated this session): dword(p, c) at p*32 + (c ^ 16*((p>>2)&1))
    // write lanes: p=8mt+2g+d -> beta=(g>>1)&1 ; read lanes: p=4g+i (+16) -> beta=g&1
    const int vw_i = 64 * g + (n ^ ((g & 2) ? 16 : 0));
    const int vr_i = 128 * g + (n ^ ((g & 1) ? 16 : 0));

    const floatx4 zero4 = {0.f, 0.f, 0.f, 0.f};

    auto mk4 = [&](const float* p, half4& h) {
#pragma unroll
        for (int j = 0; j < 4; ++j) h[j] = (_Float16)p[j];
    };
    auto mk8 = [&](const float* p, half8& h) {
#pragma unroll
        for (int j = 0; j < 8; ++j) h[j] = (_Float16)p[j];
    };

    // weights (single fp16 RTNE). wave0: wh0 (K=16 frags of W_hh0) + W_ih0 col + bias.
    // wave1: wi1 (K=32 frags of W_ih1), wh1 (K=16 frags of W_hh1), bias, W_fc.
    half4 wh0[4][4];
    half8 wi1[4][2];
    half4 wh1[4][4];
    float4 wv[4], bs[4], wfc[4];

    if (w == 0) {
#pragma unroll
        for (int mt = 0; mt < 4; ++mt) {
#pragma unroll
            for (int kt = 0; kt < 4; ++kt)
                mk4(W_hh0 + (16 * mt + n) * 64 + 16 * kt + 4 * g, wh0[mt][kt]);
            wv[mt] = *(const float4*)(W_ih0 + 16 * mt + 4 * g);
            const float4 a = *(const float4*)(b_ih0 + 16 * mt + 4 * g);
            const float4 c = *(const float4*)(b_hh0 + 16 * mt + 4 * g);
            bs[mt] = make_float4(a.x + c.x, a.y + c.y, a.z + c.z, a.w + c.w);
        }
    } else {
#pragma unroll
        for (int mt = 0; mt < 4; ++mt) {
#pragma unroll
            for (int k2 = 0; k2 < 2; ++k2)
                mk8(W_ih1 + (16 * mt + n) * 64 + 32 * k2 + 8 * g, wi1[mt][k2]);
#pragma unroll
            for (int kt = 0; kt < 4; ++kt)
                mk4(W_hh1 + (16 * mt + n) * 64 + 16 * kt + 4 * g, wh1[mt][kt]);
            const float4 a = *(const float4*)(b_ih1 + 16 * mt + 4 * g);
            const float4 c = *(const float4*)(b_hh1 + 16 * mt + 4 * g);
            bs[mt] = make_float4(a.x + c.x, a.y + c.y, a.z + c.z, a.w + c.w);
            wfc[mt] = *(const float4*)(W_fc + 16 * mt + 4 * g);
        }
    }

    // register state fragments (h0 for wave0, h1 for wave1); h(-1) = 0
    half4 st[4];
#pragma unroll
    for (int kt = 0; kt < 4; ++kt) {
        uint2 z = {0u, 0u};
        st[kt] = __builtin_bit_cast(half4, z);
    }

    const float* xp = x + (long)(b0 + n) * TT;
    float xv = 0.f, xn = 0.f;
    if (w == 0) { xv = xp[0]; xn = xp[1]; }

    // ---- layer-0 step: 16x(K=16) MFMA on register state -> tanh -> pack;
    //      packed D tiles ARE next B frags; ring write is fire-and-forget ----
    auto stepL0 = [&](int t) {
        floatx4 acc[4];
#pragma unroll
        for (int mt = 0; mt < 4; ++mt) {
            acc[mt][0] = __builtin_fmaf(xv, wv[mt].x, bs[mt].x);
            acc[mt][1] = __builtin_fmaf(xv, wv[mt].y, bs[mt].y);
            acc[mt][2] = __builtin_fmaf(xv, wv[mt].z, bs[mt].z);
            acc[mt][3] = __builtin_fmaf(xv, wv[mt].w, bs[mt].w);
        }
#pragma unroll
        for (int kt = 0; kt < 4; ++kt)
#pragma unroll
            for (int mt = 0; mt < 4; ++mt)
                acc[mt] = __builtin_amdgcn_mfma_f32_16x16x16f16(wh0[mt][kt], st[kt], acc[mt], 0, 0, 0);
        xv = xn; xn = xp[(t + 2) & (TT - 1)];
        int* wp = &lds32[(t & 7) * 1024 + vw_i];
#pragma unroll
        for (int mt = 0; mt < 4; ++mt) {
            const float h0v = fast_tanh(acc[mt][0]);
            const float h1v = fast_tanh(acc[mt][1]);
            const float h2v = fast_tanh(acc[mt][2]);
            const float h3v = fast_tanh(acc[mt][3]);
            uint2 u;
            u.x = pk16(h0v, h1v);
            u.y = pk16(h2v, h3v);
            wp[256 * mt]      = (int)u.x;
            wp[256 * mt + 32] = (int)u.y;
            st[mt] = __builtin_bit_cast(half4, u);   // next-step B fragment
        }
    };

    // ---- layer-1 step: ring reads issued first (hidden behind the hh1
    //      register-state MFMA chain), tanh -> pack stays in registers ----
    auto stepL1 = [&](int t, bool last) {
        const int* rx = &lds32[(t & 7) * 1024 + vr_i];
        int4 u0, u1;
        u0.x = rx[0];   u0.y = rx[32];  u0.z = rx[64];  u0.w = rx[96];
        u1.x = rx[512]; u1.y = rx[544]; u1.z = rx[576]; u1.w = rx[608];
        floatx4 aB[4];
#pragma unroll
        for (int mt = 0; mt < 4; ++mt) aB[mt] = zero4;
#pragma unroll
        for (int kt = 0; kt < 4; ++kt)
#pragma unroll
            for (int mt = 0; mt < 4; ++mt)
                aB[mt] = __builtin_amdgcn_mfma_f32_16x16x16f16(wh1[mt][kt], st[kt], aB[mt], 0, 0, 0);
        const half8 bx0 = __builtin_bit_cast(half8, u0);
        const half8 bx1 = __builtin_bit_cast(half8, u1);
        floatx4 aA[4];
#pragma unroll
        for (int mt = 0; mt < 4; ++mt) {
            floatx4 a = {bs[mt].x, bs[mt].y, bs[mt].z, bs[mt].w};
            a      = __builtin_amdgcn_mfma_f32_16x16x32_f16(wi1[mt][0], bx0, a, 0, 0, 0);
            aA[mt] = __builtin_amdgcn_mfma_f32_16x16x32_f16(wi1[mt][1], bx1, a, 0, 0, 0);
        }
        if (!last) {
#pragma unroll
            for (int mt = 0; mt < 4; ++mt) {
                const float h0v = fast_tanh(aA[mt][0] + aB[mt][0]);
                const float h1v = fast_tanh(aA[mt][1] + aB[mt][1]);
                const float h2v = fast_tanh(aA[mt][2] + aB[mt][2]);
                const float h3v = fast_tanh(aA[mt][3] + aB[mt][3]);
                uint2 u;
                u.x = pk16(h0v, h1v);
                u.y = pk16(h2v, h3v);
                st[mt] = __builtin_bit_cast(half4, u);   // next-step B fragment
            }
        } else {
            // final step t=511: FC dot on f32 h (same epilogue numerics)
            float p = 0.f;
#pragma unroll
            for (int mt = 0; mt < 4; ++mt) {
#pragma unroll
                for (int r = 0; r < 4; ++r)
                    p = __builtin_fmaf(fast_tanh(aA[mt][r] + aB[mt][r]), f4e(wfc[mt], r), p);
            }
            p += __shfl_xor(p, 16, 64);
            p += __shfl_xor(p, 32, 64);
            if (lane < 16) out[b0 + lane] = p + b_fc[0];
        }
    };

    // ---- supersteps: wave0 writes ring entries [4s,4s+4)&7; wave1 lags one
    //      superstep (disjoint ring halves). One raw barrier per superstep. ----
    for (int s = 0; s < 128; ++s) {
        if (w == 0) {
            const int t = 4 * s;
            stepL0(t); stepL0(t + 1); stepL0(t + 2); stepL0(t + 3);
        } else if (s > 0) {
            const int t = 4 * (s - 1);
            stepL1(t, false); stepL1(t + 1, false); stepL1(t + 2, false); stepL1(t + 3, false);
        }
        BAR();
    }
    // wave1 epilogue: entries 4..7 were written in superstep 127 (barrier passed)
    if (w == 1) {
        stepL1(508, false); stepL1(509, false); stepL1(510, false);
        stepL1(511, true);
    }
}

extern "C" void kernel_launch(void* const* d_in, const int* in_sizes, int n_in,
                              void* d_out, int out_size, void* d_ws, size_t ws_size,
                              hipStream_t stream) {
    const float* x     = (const float*)d_in[0];
    const float* W_ih0 = (const float*)d_in[1];
    const float* W_hh0 = (const float*)d_in[2];
    const float* b_ih0 = (const float*)d_in[3];
    const float* b_hh0 = (const float*)d_in[4];
    const float* W_ih1 = (const float*)d_in[5];
    const float* W_hh1 = (const float*)d_in[6];
    const float* b_ih1 = (const float*)d_in[7];
    const float* b_hh1 = (const float*)d_in[8];
    const float* W_fc  = (const float*)d_in[9];
    const float* b_fc  = (const float*)d_in[10];
    float* out = (float*)d_out;

    rnn2_reg<<<128, 128, 0, stream>>>(x, W_ih0, W_hh0, b_ih0, b_hh0,
                                      W_ih1, W_hh1, b_ih1, b_hh1,
                                      W_fc, b_fc, out);
}

// Round 3
// 296.196 us; speedup vs baseline: 1.6988x; 1.5411x over previous
//
#include <hip/hip_runtime.h>

#define TT 512

typedef _Float16 half4 __attribute__((ext_vector_type(4)));
typedef __attribute__((ext_vector_type(4))) float floatx4;

// raw workgroup barrier (no vmcnt/lgkmcnt drain); LDS FIFO is in-order per CU,
// validated R6-R12 (reads issued pre-barrier stay bit-exact vs post-barrier
// overwrites across 512 steps).
#define BAR() do { __asm__ volatile("" ::: "memory"); \
                   __builtin_amdgcn_s_barrier();      \
                   __asm__ volatile("" ::: "memory"); } while (0)

__device__ __forceinline__ float fast_tanh(float z) {
    const float e = __expf(2.f * z);
    return 1.f - __fdividef(2.f, e + 1.f);
}
__device__ __forceinline__ float f4e(const float4& v, int r) {
    return (r == 0) ? v.x : (r == 1) ? v.y : (r == 2) ? v.z : v.w;
}
__device__ __forceinline__ unsigned pk16(float a, float b) {
    const unsigned ua = __builtin_bit_cast(unsigned short, (_Float16)a);
    const unsigned ub = __builtin_bit_cast(unsigned short, (_Float16)b);
    return ua | (ub << 16);
}

// H-split + register-identity hybrid: 128 blocks x 4 waves, 16 batch rows/block.
// Wave wq owns h-rows [16wq,16wq+16) of BOTH layers (L0 at t, L1 at t-2: two
// independent dep chains per wave). K=64 recurrence = 4 accumulating K=16 MFMAs;
// the D->B fragment identity (verified R2: tanh'd+fp16-packed D tile IS the
// next-step B fragment) keeps the OWN fragment in registers; only the 3 partner
// fragments cross LDS (lag-1, exposed ~1 read latency, hidden under 6
// register-operand MFMAs). L1's h0(t-2) input = the SAME partner values L0 read
// one interval earlier (kept in regs) + own-fragment history -> no extra reads.
// One raw 4-wave barrier per interval. LDS layout: uint2(rowquad rq, col n) at
// rq*16+n -> every 16-lane quarter-wave covers all 32 banks (conflict-free).
// Numerics: identical fp16-RTNE state path as R10/R2; f32 add order only.
__global__ void __launch_bounds__(256, 1)
rnn2_hy(const float* __restrict__ x,
        const float* __restrict__ W_ih0, const float* __restrict__ W_hh0,
        const float* __restrict__ b_ih0, const float* __restrict__ b_hh0,
        const float* __restrict__ W_ih1, const float* __restrict__ W_hh1,
        const float* __restrict__ b_ih1, const float* __restrict__ b_hh1,
        const float* __restrict__ W_fc, const float* __restrict__ b_fc,
        float* __restrict__ out)
{
    __shared__ uint2 h0buf[2][256];   // [parity][(4*wq+g)*16 + n]
    __shared__ uint2 h1buf[2][256];
    __shared__ float red[4][16];

    const int tid  = threadIdx.x;
    const int lane = tid & 63;
    const int wq   = tid >> 6;    // wave: h-row tile [16wq, 16wq+16)
    const int g    = lane >> 4;   // row-quad within tile
    const int n    = lane & 15;   // batch column
    const int b0   = blockIdx.x * 16;

    // zero-init both parities of both state buffers
    {
        uint2 z; z.x = 0u; z.y = 0u;
        ((uint2*)h0buf)[tid]       = z;
        ((uint2*)h0buf)[tid + 256] = z;
        ((uint2*)h1buf)[tid]       = z;
        ((uint2*)h1buf)[tid + 256] = z;
    }

    // ---- weights, fp16 RTNE, rotated so index s=0 is the OWN fragment ----
    half4 wh0r[4], wi1r[4], wh1r[4];
    auto mk4 = [&](const float* p, half4& h) {
#pragma unroll
        for (int j = 0; j < 4; ++j) h[j] = (_Float16)p[j];
    };
#pragma unroll
    for (int s = 0; s < 4; ++s) {
        const int kt = (wq + s) & 3;
        mk4(W_hh0 + (16 * wq + n) * 64 + 16 * kt + 4 * g, wh0r[s]);
        mk4(W_ih1 + (16 * wq + n) * 64 + 16 * kt + 4 * g, wi1r[s]);
        mk4(W_hh1 + (16 * wq + n) * 64 + 16 * kt + 4 * g, wh1r[s]);
    }
    const float4 wv = *(const float4*)(W_ih0 + 16 * wq + 4 * g);
    float4 bs0, bs1;
    {
        const float4 a = *(const float4*)(b_ih0 + 16 * wq + 4 * g);
        const float4 c = *(const float4*)(b_hh0 + 16 * wq + 4 * g);
        bs0 = make_float4(a.x + c.x, a.y + c.y, a.z + c.z, a.w + c.w);
        const float4 d = *(const float4*)(b_ih1 + 16 * wq + 4 * g);
        const float4 e = *(const float4*)(b_hh1 + 16 * wq + 4 * g);
        bs1 = make_float4(d.x + e.x, d.y + e.y, d.z + e.z, d.w + e.w);
    }
    const float4 wfc = *(const float4*)(W_fc + 16 * wq + 4 * g);

    // state fragments (own tiles, registers); h(-1)=0
    const uint2 z2 = {0u, 0u};
    half4 st0 = __builtin_bit_cast(half4, z2);   // own h0(latest)
    half4 st1 = __builtin_bit_cast(half4, z2);   // own h1(latest)
    half4 own0d = st0;                           // own h0(i-2) for L1 input
    half4 r0d1 = st0, r0d2 = st0, r0d3 = st0;    // partner h0(i-2) for L1 input

    const float* xp = x + (long)(b0 + n) * TT;
    float xv = xp[0], xn = xp[1];

    const int k1 = (wq + 1) & 3, k2 = (wq + 2) & 3, k3 = (wq + 3) & 3;
    const int ri1 = (4 * k1 + g) * 16 + n;
    const int ri2 = (4 * k2 + g) * 16 + n;
    const int ri3 = (4 * k3 + g) * 16 + n;
    const int wi  = (4 * wq + g) * 16 + n;

    __syncthreads();   // one full barrier after zero-init

    auto body = [&](int i, bool doL0, bool doL1, bool last) {
        const int P = i & 1, R = P ^ 1;
        // lag-1 partner reads (exposed; hidden under register-operand MFMAs)
        uint2 q0a, q0b, q0c, q1a, q1b, q1c;
        if (!last) {
            q0a = h0buf[R][ri1];
            q0b = h0buf[R][ri2];
            q0c = h0buf[R][ri3];
        }
        if (doL1) {
            q1a = h1buf[R][ri1];
            q1b = h1buf[R][ri2];
            q1c = h1buf[R][ri3];
        }
        // L1: 5 register-operand MFMAs issue with no LDS dependency
        floatx4 a1;
        if (doL1) {
            a1[0] = bs1.x; a1[1] = bs1.y; a1[2] = bs1.z; a1[3] = bs1.w;
            a1 = __builtin_amdgcn_mfma_f32_16x16x16f16(wi1r[0], own0d, a1, 0, 0, 0);
            a1 = __builtin_amdgcn_mfma_f32_16x16x16f16(wi1r[1], r0d1, a1, 0, 0, 0);
            a1 = __builtin_amdgcn_mfma_f32_16x16x16f16(wi1r[2], r0d2, a1, 0, 0, 0);
            a1 = __builtin_amdgcn_mfma_f32_16x16x16f16(wi1r[3], r0d3, a1, 0, 0, 0);
            a1 = __builtin_amdgcn_mfma_f32_16x16x16f16(wh1r[0], st1, a1, 0, 0, 0);
        }
        floatx4 a0;
        if (doL0) {
            a0[0] = __builtin_fmaf(xv, wv.x, bs0.x);
            a0[1] = __builtin_fmaf(xv, wv.y, bs0.y);
            a0[2] = __builtin_fmaf(xv, wv.z, bs0.z);
            a0[3] = __builtin_fmaf(xv, wv.w, bs0.w);
            a0 = __builtin_amdgcn_mfma_f32_16x16x16f16(wh0r[0], st0, a0, 0, 0, 0);  // own, no wait
            a0 = __builtin_amdgcn_mfma_f32_16x16x16f16(wh0r[1], __builtin_bit_cast(half4, q0a), a0, 0, 0, 0);
            a0 = __builtin_amdgcn_mfma_f32_16x16x16f16(wh0r[2], __builtin_bit_cast(half4, q0b), a0, 0, 0, 0);
            a0 = __builtin_amdgcn_mfma_f32_16x16x16f16(wh0r[3], __builtin_bit_cast(half4, q0c), a0, 0, 0, 0);
            xv = xn; xn = xp[(i + 2) & (TT - 1)];
        }
        if (doL1) {
            a1 = __builtin_amdgcn_mfma_f32_16x16x16f16(wh1r[1], __builtin_bit_cast(half4, q1a), a1, 0, 0, 0);
            a1 = __builtin_amdgcn_mfma_f32_16x16x16f16(wh1r[2], __builtin_bit_cast(half4, q1b), a1, 0, 0, 0);
            a1 = __builtin_amdgcn_mfma_f32_16x16x16f16(wh1r[3], __builtin_bit_cast(half4, q1c), a1, 0, 0, 0);
        }
        // shift the lag-2 h0 window: this interval's h0(i-1) becomes next bp
        if (!last) {
            own0d = st0;
            r0d1 = __builtin_bit_cast(half4, q0a);
            r0d2 = __builtin_bit_cast(half4, q0b);
            r0d3 = __builtin_bit_cast(half4, q0c);
        }
        if (doL0) {
            uint2 u;
            u.x = pk16(fast_tanh(a0[0]), fast_tanh(a0[1]));
            u.y = pk16(fast_tanh(a0[2]), fast_tanh(a0[3]));
            h0buf[P][wi] = u;
            st0 = __builtin_bit_cast(half4, u);    // own frag, register-resident
        }
        if (doL1) {
            if (!last) {
                uint2 u;
                u.x = pk16(fast_tanh(a1[0]), fast_tanh(a1[1]));
                u.y = pk16(fast_tanh(a1[2]), fast_tanh(a1[3]));
                h1buf[P][wi] = u;
                st1 = __builtin_bit_cast(half4, u);
            } else {
                // h1(511) + FC partial for own 16 rows
                float p = 0.f;
#pragma unroll
                for (int r = 0; r < 4; ++r)
                    p = __builtin_fmaf(fast_tanh(a1[r]), f4e(wfc, r), p);
                p += __shfl_xor(p, 16, 64);
                p += __shfl_xor(p, 32, 64);
                if (lane < 16) red[wq][n] = p;
            }
        }
    };

    // pipeline fill: L1 inactive until its inputs exist
    body(0, true, false, false); BAR();
    body(1, true, false, false); BAR();
    // steady state: L0 at t=i, L1 at t=i-2
    for (int i = 2; i < 512; i += 2) {
        body(i,     true, true, false); BAR();
        body(i + 1, true, true, false); BAR();
    }
    // drain: L1 computes h1(510), then h1(511)+FC
    body(512, false, true, false); BAR();
    body(513, false, true, true);
    __syncthreads();
    if (wq == 0 && lane < 16)
        out[b0 + n] = red[0][n] + red[1][n] + red[2][n] + red[3][n] + b_fc[0];
}

extern "C" void kernel_launch(void* const* d_in, const int* in_sizes, int n_in,
                              void* d_out, int out_size, void* d_ws, size_t ws_size,
                              hipStream_t stream) {
    const float* x     = (const float*)d_in[0];
    const float* W_ih0 = (const float*)d_in[1];
    const float* W_hh0 = (const float*)d_in[2];
    const float* b_ih0 = (const float*)d_in[3];
    const float* b_hh0 = (const float*)d_in[4];
    const float* W_ih1 = (const float*)d_in[5];
    const float* W_hh1 = (const float*)d_in[6];
    const float* b_ih1 = (const float*)d_in[7];
    const float* b_hh1 = (const float*)d_in[8];
    const float* W_fc  = (const float*)d_in[9];
    const float* b_fc  = (const float*)d_in[10];
    float* out = (float*)d_out;

    rnn2_hy<<<128, 256, 0, stream>>>(x, W_ih0, W_hh0, b_ih0, b_hh0,
                                     W_ih1, W_hh1, b_ih1, b_hh1,
                                     W_fc, b_fc, out);
}